// Round 6
// baseline (689.954 us; speedup 1.0000x reference)
//
#include <hip/hip_runtime.h>
#include <math.h>

// ---------------------------------------------------------------------------
// Griffin block (Hawk recurrent branch + GatedMLP) for MI355X / gfx950.
// bf16 MFMA GEMMs; alpha/xg recomputed in fused scan passes (no f32 buffers).
// Peak workspace: 170.5 MB (was 313 MB -> suspected OOB abort in round 2).
// ---------------------------------------------------------------------------

using u16 = unsigned short;
using u32 = unsigned int;

typedef __bf16 bf16x8 __attribute__((ext_vector_type(8)));
typedef float  f32x4  __attribute__((ext_vector_type(4)));
typedef u16    u16x4  __attribute__((ext_vector_type(4)));
typedef u16    u16x8  __attribute__((ext_vector_type(8)));

#define DIMD 1024
#define HIDD 1536
#define GHIDD 2048
#define ROWS 8192        // N*T
#define TLEN 2048
#define CH   32          // scan chunk length
#define NCH  64          // chunks per sequence (2048/32)

__device__ __forceinline__ u16 f2b(float f) {          // f32 -> bf16 RNE
    union { float f; u32 u; } x; x.f = f;
    u32 r = x.u + 0x7fffu + ((x.u >> 16) & 1u);
    return (u16)(r >> 16);
}
__device__ __forceinline__ float b2f(u16 u) {
    union { u32 u; float f; } x; x.u = ((u32)u) << 16;
    return x.f;
}
__device__ __forceinline__ float gelu_exact(float g) {
    return 0.5f * g * (1.f + erff(g * 0.70710678118654752f));
}
__device__ __forceinline__ float sigmoidf_(float x) {
    return 1.f / (1.f + expf(-x));
}

// ---------------------------------------------------------------------------
// f32 -> bf16 conversion (weights)
// ---------------------------------------------------------------------------
__global__ __launch_bounds__(256)
void cvt_k(const float* __restrict__ s, u16* __restrict__ d, long n) {
    long i = ((long)blockIdx.x * 256 + threadIdx.x) * 4;
    if (i >= n) return;
    f32x4 v = *reinterpret_cast<const f32x4*>(s + i);
    u16x4 o;
    #pragma unroll
    for (int e = 0; e < 4; e++) o[e] = f2b(v[e]);
    *reinterpret_cast<u16x4*>(d + i) = o;
}

// ---------------------------------------------------------------------------
// RMSNorm (row = 1024 f32) -> bf16.  out = gamma * sqrt(1024) * x / ||x||
// ---------------------------------------------------------------------------
__global__ __launch_bounds__(256)
void rmsnorm_k(const float* __restrict__ x, const float* __restrict__ gamma,
               u16* __restrict__ out) {
    const int row = blockIdx.x;
    const int tid = threadIdx.x;
    const float* xr = x + (long)row * DIMD;
    f32x4 v = *reinterpret_cast<const f32x4*>(xr + tid * 4);
    float ss = v[0]*v[0] + v[1]*v[1] + v[2]*v[2] + v[3]*v[3];
    #pragma unroll
    for (int o = 32; o > 0; o >>= 1) ss += __shfl_xor(ss, o);
    __shared__ float red[4];
    if ((tid & 63) == 0) red[tid >> 6] = ss;
    __syncthreads();
    float tot = red[0] + red[1] + red[2] + red[3];
    float scale = 32.f / sqrtf(tot);          // sqrt(1024) / ||x||
    f32x4 gv = *reinterpret_cast<const f32x4*>(gamma + tid * 4);
    u16x4 o4;
    #pragma unroll
    for (int e = 0; e < 4; e++) o4[e] = f2b(v[e] * scale * gv[e]);
    *reinterpret_cast<u16x4*>(out + (long)row * DIMD + tid * 4) = o4;
}

// ---------------------------------------------------------------------------
// bf16 GEMM: C[M,N] = A[M,K] * B[N,K]^T  (+bias[col]) (+res[row,col])
// m97 structure: 128x128 tile, BK=64, 4 waves, global_load_lds width 16,
// T2 XOR swizzle (linear LDS dest + inverse-swizzled global src + swz read).
// SPLIT epilogue (gemm1): col<HIDD -> Cout=gelu(v) bf16; else Cout2=v bf16,
// both compact [M,HIDD].
// ---------------------------------------------------------------------------
template<bool BIAS, bool RES, bool OBF16, bool SPLIT>
__global__ __launch_bounds__(256)
void gemm_bt(const u16* __restrict__ A, const u16* __restrict__ B,
             const float* __restrict__ bias, const float* __restrict__ res,
             void* __restrict__ Cout, void* __restrict__ Cout2,
             int M, int N, int K) {
    constexpr int BK = 64;
    __shared__ alignas(16) u16 As[128 * BK];
    __shared__ alignas(16) u16 Bs[128 * BK];

    const int tid  = threadIdx.x;
    const int wave = tid >> 6;
    const int lane = tid & 63;
    const int lhi  = lane >> 4;        // k-group 0..3
    const int llo  = lane & 15;        // row/col within fragment
    const int wm   = wave >> 1, wn = wave & 1;
    const long tileM = (long)blockIdx.y * 128;
    const long tileN = (long)blockIdx.x * 128;

    // staging geometry: chunk = wave*4+i covers rows chunk*8..+7, 1KB each.
    // row&7 == lane>>3, so swizzled unit su is lane-constant.
    const int ldrow = lane >> 3;
    const int su    = (lane & 7) ^ ldrow;          // XOR-swizzled 16B unit
    const u16* gA = A + (tileM + wave * 32 + ldrow) * (long)K + su * 8;
    const u16* gB = B + (tileN + wave * 32 + ldrow) * (long)K + su * 8;
    u16* lAw = As + wave * 2048;                   // wave chunk base (ushorts)
    u16* lBw = Bs + wave * 2048;

    const f32x4 zero = {0.f, 0.f, 0.f, 0.f};
    f32x4 acc[4][4];
    #pragma unroll
    for (int m = 0; m < 4; m++)
        #pragma unroll
        for (int n = 0; n < 4; n++) acc[m][n] = zero;

    const int rsel = llo & 7;                      // read-side swizzle key

    for (int kt = 0; kt < K; kt += BK) {
        #pragma unroll
        for (int i = 0; i < 4; i++) {
            __builtin_amdgcn_global_load_lds(
                (const __attribute__((address_space(1))) void*)(gA + (long)(i*8)*K + kt),
                (__attribute__((address_space(3))) void*)(lAw + i * 512), 16, 0, 0);
            __builtin_amdgcn_global_load_lds(
                (const __attribute__((address_space(1))) void*)(gB + (long)(i*8)*K + kt),
                (__attribute__((address_space(3))) void*)(lBw + i * 512), 16, 0, 0);
        }
        __syncthreads();
        #pragma unroll
        for (int kk = 0; kk < 2; kk++) {
            bf16x8 af[4], bfr[4];
            #pragma unroll
            for (int m = 0; m < 4; m++) {
                int row  = wm * 64 + m * 16 + llo;
                int slot = (kk * 4 + lhi) ^ rsel;
                af[m] = *reinterpret_cast<const bf16x8*>(As + row * BK + slot * 8);
            }
            #pragma unroll
            for (int n = 0; n < 4; n++) {
                int col  = wn * 64 + n * 16 + llo;
                int slot = (kk * 4 + lhi) ^ rsel;
                bfr[n] = *reinterpret_cast<const bf16x8*>(Bs + col * BK + slot * 8);
            }
            #pragma unroll
            for (int m = 0; m < 4; m++)
                #pragma unroll
                for (int n = 0; n < 4; n++)
                    acc[m][n] = __builtin_amdgcn_mfma_f32_16x16x32_bf16(
                        af[m], bfr[n], acc[m][n], 0, 0, 0);
        }
        __syncthreads();
    }

    // epilogue: C/D layout col = lane&15, row = (lane>>4)*4 + r  [m89-verified]
    #pragma unroll
    for (int n = 0; n < 4; n++) {
        const long col = tileN + wn * 64 + n * 16 + llo;
        float bv = BIAS ? bias[col] : 0.f;
        #pragma unroll
        for (int m = 0; m < 4; m++) {
            const long row0 = tileM + wm * 64 + m * 16 + lhi * 4;
            #pragma unroll
            for (int r = 0; r < 4; r++) {
                const long row = row0 + r;
                float v = acc[m][n][r] + bv;
                if (SPLIT) {
                    if (col < HIDD)
                        ((u16*)Cout)[row * HIDD + col] = f2b(gelu_exact(v));
                    else
                        ((u16*)Cout2)[row * HIDD + (col - HIDD)] = f2b(v);
                } else {
                    long off = row * N + col;
                    if (RES)   v += res[off];
                    if (OBF16) ((u16*)Cout)[off] = f2b(v);
                    else       ((float*)Cout)[off] = v;
                }
            }
        }
    }
}

// ---------------------------------------------------------------------------
// Causal depthwise conv K=4 over T, per (n,t, 8 channels). vr: [ROWS, HIDD]
// ---------------------------------------------------------------------------
__global__ __launch_bounds__(256)
void conv_k(const u16* __restrict__ vr, const float* __restrict__ cw,
            const float* __restrict__ cb, u16* __restrict__ vout) {
    int idx = blockIdx.x * 256 + threadIdx.x;      // ROWS * 192
    int hb  = (idx % 192) * 8;
    int row = idx / 192;
    int t   = row & (TLEN - 1);
    float acc[8];
    #pragma unroll
    for (int e = 0; e < 8; e++) acc[e] = cb[hb + e];
    #pragma unroll
    for (int j = 0; j < 4; j++) {
        int dt = 3 - j;
        if (t >= dt) {
            u16x8 v = *reinterpret_cast<const u16x8*>(
                vr + (long)(row - dt) * HIDD + hb);
            #pragma unroll
            for (int e = 0; e < 8; e++)
                acc[e] = fmaf(b2f(v[e]), cw[(hb + e) * 4 + j], acc[e]);
        }
    }
    u16x8 o;
    #pragma unroll
    for (int e = 0; e < 8; e++) o[e] = f2b(acc[e]);
    *reinterpret_cast<u16x8*>(vout + (long)row * HIDD + hb) = o;
}

// ---------------------------------------------------------------------------
// Fused scan phase A: recompute alpha/xg from g (forget,inp) + vconv, reduce
// chunk to (A = prod alpha, b = chunk-local scan end value).
// ---------------------------------------------------------------------------
__global__ __launch_bounds__(256)
void scanA_k(const u16* __restrict__ g, const u16* __restrict__ vc,
             const float* __restrict__ fb, float* __restrict__ Ac,
             float* __restrict__ bc) {
    int idx = blockIdx.x * 256 + threadIdx.x;      // 4*NCH*HID = 393216
    int h   = idx % HIDD;
    int nc  = idx / HIDD;                          // n*NCH + c
    const float c = -8.f * log1pf(expf(fb[h]));    // -8*softplus(fbase)
    long row = (long)nc * CH;
    float A = 1.f, b = 0.f;
    for (int t = 0; t < CH; t++, row++) {
        float fg = b2f(g[row * (2*HIDD) + h]);
        float ip = b2f(g[row * (2*HIDD) + HIDD + h]);
        float vv = b2f(vc[row * HIDD + h]);
        float a  = expf(c * sigmoidf_(fg));
        float be = sqrtf(1.f - a * a + 1e-6f);
        float x  = be * sigmoidf_(ip) * vv;
        A *= a;
        b = fmaf(a, b, x);
    }
    Ac[idx] = A;
    bc[idx] = b;
}

__global__ __launch_bounds__(256)
void scanB_k(const float* __restrict__ Ac, const float* __restrict__ bc,
             float* __restrict__ carry) {
    int idx = blockIdx.x * 256 + threadIdx.x;      // 4*HID = 6144
    if (idx >= 4 * HIDD) return;
    int n = idx / HIDD, h = idx % HIDD;
    float H = 0.f;
    #pragma unroll 8
    for (int c = 0; c < NCH; c++) {
        long o = (long)(n * NCH + c) * HIDD + h;
        carry[o] = H;
        H = fmaf(Ac[o], H, bc[o]);
    }
}

// ---------------------------------------------------------------------------
// Fused scan phase C: recompute alpha/xg, finish scan from carry, multiply by
// precomputed gelu(gate) (gg) -> bf16 gh (GEMM3 A-operand).
// ---------------------------------------------------------------------------
__global__ __launch_bounds__(256)
void scanC_k(const u16* __restrict__ g, const u16* __restrict__ vc,
             const float* __restrict__ fb, const float* __restrict__ carry,
             const u16* __restrict__ gg, u16* __restrict__ gh) {
    int idx = blockIdx.x * 256 + threadIdx.x;      // 4*NCH*HID
    int h   = idx % HIDD;
    int nc  = idx / HIDD;
    const float c = -8.f * log1pf(expf(fb[h]));
    float H = carry[idx];
    long row = (long)nc * CH;
    for (int t = 0; t < CH; t++, row++) {
        float fg = b2f(g[row * (2*HIDD) + h]);
        float ip = b2f(g[row * (2*HIDD) + HIDD + h]);
        float vv = b2f(vc[row * HIDD + h]);
        float a  = expf(c * sigmoidf_(fg));
        float be = sqrtf(1.f - a * a + 1e-6f);
        float x  = be * sigmoidf_(ip) * vv;
        H = fmaf(a, H, x);
        float gv = b2f(gg[row * HIDD + h]);
        gh[row * HIDD + h] = f2b(gv * H);
    }
}

// ---------------------------------------------------------------------------
// m2 = gelu(grow[:, :GHID]) * grow[:, GHID:]  -> bf16
// ---------------------------------------------------------------------------
__global__ __launch_bounds__(256)
void glumul_k(const u16* __restrict__ grow, u16* __restrict__ m2) {
    long idx = ((long)blockIdx.x * 256 + threadIdx.x) * 4;  // ROWS*GHID
    int row = (int)(idx >> 11);                    // /2048
    int h   = (int)(idx & (GHIDD - 1));
    u16x4 gt = *reinterpret_cast<const u16x4*>(grow + (long)row * (2*GHIDD) + h);
    u16x4 vv = *reinterpret_cast<const u16x4*>(grow + (long)row * (2*GHIDD) + GHIDD + h);
    u16x4 o;
    #pragma unroll
    for (int e = 0; e < 4; e++)
        o[e] = f2b(gelu_exact(b2f(gt[e])) * b2f(vv[e]));
    *reinterpret_cast<u16x4*>(m2 + idx) = o;
}

// ---------------------------------------------------------------------------
// Launch
// ---------------------------------------------------------------------------
extern "C" void kernel_launch(void* const* d_in, const int* in_sizes, int n_in,
                              void* d_out, int out_size, void* d_ws, size_t ws_size,
                              hipStream_t stream) {
    (void)in_sizes; (void)n_in; (void)out_size; (void)ws_size;
    const float* x        = (const float*)d_in[0];
    const float* gamma1   = (const float*)d_in[1];
    const float* W_in     = (const float*)d_in[2];
    const float* conv_w   = (const float*)d_in[3];
    const float* conv_b   = (const float*)d_in[4];
    const float* W_gates  = (const float*)d_in[5];
    const float* b_gates  = (const float*)d_in[6];
    const float* fbase    = (const float*)d_in[7];
    const float* W_out    = (const float*)d_in[8];
    const float* gamma2   = (const float*)d_in[9];
    const float* W_grow   = (const float*)d_in[10];
    const float* W_shrink = (const float*)d_in[11];

    char* ws = (char*)d_ws;
    // workspace layout (bytes), peak 178,782,208 (~170.5 MB), with aliasing:
    //   vr (gemm1..conv) then gh (scanC..gemm3) share one 25.2 MB slot;
    //   grow (gemm4..glumul) overlays gg+gh+vc (all dead by then);
    //   m2 (glumul..gemm5) overlays g; x2 residual stream lives in d_out.
    u16*   w_in_b    = (u16*)(ws + 0);                 //  6,291,456
    u16*   w_gates_b = (u16*)(ws + 6291456);           //  9,437,184
    u16*   w_out_b   = (u16*)(ws + 15728640);          //  3,145,728
    u16*   w_grow_b  = (u16*)(ws + 18874368);          //  8,388,608
    u16*   w_shr_b   = (u16*)(ws + 27262976);          //  4,194,304
    u16*   xn_b      = (u16*)(ws + 31457280);          // 16.8 MB (xn1 / xn2)
    u16*   gg_b      = (u16*)(ws + 48234496);          // 25.2 MB gelu(gate)
    u16*   vr_b      = (u16*)(ws + 73400320);          // 25.2 MB v raw
    u16*   gh_b      = (u16*)(ws + 73400320);          // alias (vr dead)
    u16*   vc_b      = (u16*)(ws + 98566144);          // 25.2 MB v conv
    u16*   g_b       = (u16*)(ws + 123731968);         // 50.3 MB gates
    u16*   grow_b    = (u16*)(ws + 48234496);          // alias gg..vc (67.1MB)
    u16*   m2_b      = (u16*)(ws + 123731968);         // alias g (33.6 MB)
    float* Ac_f      = (float*)(ws + 174063616);       // 1.57 MB
    float* bc_f      = (float*)(ws + 175636480);       // 1.57 MB
    float* carry_f   = (float*)(ws + 177209344);       // 1.57 MB -> 178,782,208
    float* x2_f      = (float*)d_out;                  // residual stream

    // --- weight conversion ---
    cvt_k<<<3072, 256, 0, stream>>>(W_in,     w_in_b,    (long)3072*1024);
    cvt_k<<<4608, 256, 0, stream>>>(W_gates,  w_gates_b, (long)3072*1536);
    cvt_k<<<1536, 256, 0, stream>>>(W_out,    w_out_b,   (long)1024*1536);
    cvt_k<<<4096, 256, 0, stream>>>(W_grow,   w_grow_b,  (long)4096*1024);
    cvt_k<<<2048, 256, 0, stream>>>(W_shrink, w_shr_b,   (long)1024*2048);

    // --- Hawk branch ---
    rmsnorm_k<<<ROWS, 256, 0, stream>>>(x, gamma1, xn_b);
    gemm_bt<false,false,true,true><<<dim3(3072/128, ROWS/128), 256, 0, stream>>>(
        xn_b, w_in_b, nullptr, nullptr, gg_b, vr_b, ROWS, 3072, 1024);
    conv_k<<<ROWS*192/256, 256, 0, stream>>>(vr_b, conv_w, conv_b, vc_b);
    gemm_bt<true,false,true,false><<<dim3(3072/128, ROWS/128), 256, 0, stream>>>(
        vc_b, w_gates_b, b_gates, nullptr, g_b, nullptr, ROWS, 3072, 1536);
    scanA_k<<<4*NCH*HIDD/256, 256, 0, stream>>>(g_b, vc_b, fbase, Ac_f, bc_f);
    scanB_k<<<24, 256, 0, stream>>>(Ac_f, bc_f, carry_f);
    scanC_k<<<4*NCH*HIDD/256, 256, 0, stream>>>(g_b, vc_b, fbase, carry_f,
                                                gg_b, gh_b);
    gemm_bt<false,true,false,false><<<dim3(1024/128, ROWS/128), 256, 0, stream>>>(
        gh_b, w_out_b, nullptr, x, x2_f, nullptr, ROWS, 1024, 1536);

    // --- GatedMLP branch ---
    rmsnorm_k<<<ROWS, 256, 0, stream>>>(x2_f, gamma2, xn_b);
    gemm_bt<false,false,true,false><<<dim3(4096/128, ROWS/128), 256, 0, stream>>>(
        xn_b, w_grow_b, nullptr, nullptr, grow_b, nullptr, ROWS, 4096, 1024);
    glumul_k<<<(long)ROWS*GHIDD/4/256, 256, 0, stream>>>(grow_b, m2_b);
    gemm_bt<false,true,false,false><<<dim3(1024/128, ROWS/128), 256, 0, stream>>>(
        m2_b, w_shr_b, nullptr, x2_f, (float*)d_out, nullptr, ROWS, 1024, 2048);
}

// Round 7
// 686.600 us; speedup vs baseline: 1.0049x; 1.0049x over previous
//
#include <hip/hip_runtime.h>
#include <math.h>

// ---------------------------------------------------------------------------
// Griffin block (Hawk recurrent branch + GatedMLP) for MI355X / gfx950.
// R7: GEMM gets (a) double-buffered LDS with counted vmcnt(8) pipeline
// (T3-minimum 2-phase + T4) and (b) XCD-aware block swizzle (T1).
// Baseline R6: 690 us, GEMMs ~75% at MfmaUtil 15% (barrier-drain bound).
// ---------------------------------------------------------------------------

using u16 = unsigned short;
using u32 = unsigned int;

typedef __bf16 bf16x8 __attribute__((ext_vector_type(8)));
typedef float  f32x4  __attribute__((ext_vector_type(4)));
typedef u16    u16x4  __attribute__((ext_vector_type(4)));
typedef u16    u16x8  __attribute__((ext_vector_type(8)));

#define DIMD 1024
#define HIDD 1536
#define GHIDD 2048
#define ROWS 8192        // N*T
#define TLEN 2048
#define CH   32          // scan chunk length
#define NCH  64          // chunks per sequence (2048/32)

__device__ __forceinline__ u16 f2b(float f) {          // f32 -> bf16 RNE
    union { float f; u32 u; } x; x.f = f;
    u32 r = x.u + 0x7fffu + ((x.u >> 16) & 1u);
    return (u16)(r >> 16);
}
__device__ __forceinline__ float b2f(u16 u) {
    union { u32 u; float f; } x; x.u = ((u32)u) << 16;
    return x.f;
}
__device__ __forceinline__ float gelu_exact(float g) {
    return 0.5f * g * (1.f + erff(g * 0.70710678118654752f));
}
__device__ __forceinline__ float sigmoidf_(float x) {
    return 1.f / (1.f + expf(-x));
}

// ---------------------------------------------------------------------------
// f32 -> bf16 conversion (weights)
// ---------------------------------------------------------------------------
__global__ __launch_bounds__(256)
void cvt_k(const float* __restrict__ s, u16* __restrict__ d, long n) {
    long i = ((long)blockIdx.x * 256 + threadIdx.x) * 4;
    if (i >= n) return;
    f32x4 v = *reinterpret_cast<const f32x4*>(s + i);
    u16x4 o;
    #pragma unroll
    for (int e = 0; e < 4; e++) o[e] = f2b(v[e]);
    *reinterpret_cast<u16x4*>(d + i) = o;
}

// ---------------------------------------------------------------------------
// RMSNorm (row = 1024 f32) -> bf16.  out = gamma * sqrt(1024) * x / ||x||
// ---------------------------------------------------------------------------
__global__ __launch_bounds__(256)
void rmsnorm_k(const float* __restrict__ x, const float* __restrict__ gamma,
               u16* __restrict__ out) {
    const int row = blockIdx.x;
    const int tid = threadIdx.x;
    const float* xr = x + (long)row * DIMD;
    f32x4 v = *reinterpret_cast<const f32x4*>(xr + tid * 4);
    float ss = v[0]*v[0] + v[1]*v[1] + v[2]*v[2] + v[3]*v[3];
    #pragma unroll
    for (int o = 32; o > 0; o >>= 1) ss += __shfl_xor(ss, o);
    __shared__ float red[4];
    if ((tid & 63) == 0) red[tid >> 6] = ss;
    __syncthreads();
    float tot = red[0] + red[1] + red[2] + red[3];
    float scale = 32.f / sqrtf(tot);          // sqrt(1024) / ||x||
    f32x4 gv = *reinterpret_cast<const f32x4*>(gamma + tid * 4);
    u16x4 o4;
    #pragma unroll
    for (int e = 0; e < 4; e++) o4[e] = f2b(v[e] * scale * gv[e]);
    *reinterpret_cast<u16x4*>(out + (long)row * DIMD + tid * 4) = o4;
}

// ---------------------------------------------------------------------------
// bf16 GEMM: C[M,N] = A[M,K] * B[N,K]^T  (+bias[col]) (+res[row,col])
// 128x128 tile, BK=64, 4 waves, global_load_lds width 16, XOR swizzle
// (verified: SQ_LDS_BANK_CONFLICT = 0).
// R7: 2-phase double-buffered pipeline — issue next-tile loads, wait
// vmcnt(8) (current tile's 8 loads done, next 8 stay in flight), barrier,
// compute. T1 XCD swizzle on block ids (all grids divisible by 8).
// ---------------------------------------------------------------------------
template<bool BIAS, bool RES, bool OBF16, bool SPLIT>
__global__ __launch_bounds__(256)
void gemm_bt(const u16* __restrict__ A, const u16* __restrict__ B,
             const float* __restrict__ bias, const float* __restrict__ res,
             void* __restrict__ Cout, void* __restrict__ Cout2,
             int M, int N, int K) {
    constexpr int BK = 64;
    __shared__ alignas(16) u16 As[2][128 * BK];   // 2 x 16 KB
    __shared__ alignas(16) u16 Bs[2][128 * BK];   // 2 x 16 KB  (total 64 KB)

    const int tid  = threadIdx.x;
    const int wave = tid >> 6;
    const int lane = tid & 63;
    const int lhi  = lane >> 4;        // k-group 0..3
    const int llo  = lane & 15;        // row/col within fragment
    const int wm   = wave >> 1, wn = wave & 1;

    // T1: XCD-aware swizzle. nwg % 8 == 0 for every grid we launch.
    const int gx  = gridDim.x;
    const int nwg = gx * gridDim.y;
    int bid = blockIdx.y * gx + blockIdx.x;
    bid = (bid & 7) * (nwg >> 3) + (bid >> 3);
    const long tileM = (long)(bid / gx) * 128;
    const long tileN = (long)(bid % gx) * 128;

    // staging geometry: chunk = wave*4+i covers rows chunk*8..+7, 1KB each.
    // row&7 == lane>>3, so swizzled unit su is lane-constant.
    const int ldrow = lane >> 3;
    const int su    = (lane & 7) ^ ldrow;          // XOR-swizzled 16B unit
    const u16* gA = A + (tileM + wave * 32 + ldrow) * (long)K + su * 8;
    const u16* gB = B + (tileN + wave * 32 + ldrow) * (long)K + su * 8;

    const f32x4 zero = {0.f, 0.f, 0.f, 0.f};
    f32x4 acc[4][4];
    #pragma unroll
    for (int m = 0; m < 4; m++)
        #pragma unroll
        for (int n = 0; n < 4; n++) acc[m][n] = zero;

    const int rsel = llo & 7;                      // read-side swizzle key

    // stage one K-tile (8 global_load_lds per wave) into buffer bsel
    auto stage = [&](int bsel, int kt) {
        u16* lAw = &As[bsel][wave * 2048];
        u16* lBw = &Bs[bsel][wave * 2048];
        #pragma unroll
        for (int i = 0; i < 4; i++) {
            __builtin_amdgcn_global_load_lds(
                (const __attribute__((address_space(1))) void*)(gA + (long)(i*8)*K + kt),
                (__attribute__((address_space(3))) void*)(lAw + i * 512), 16, 0, 0);
            __builtin_amdgcn_global_load_lds(
                (const __attribute__((address_space(1))) void*)(gB + (long)(i*8)*K + kt),
                (__attribute__((address_space(3))) void*)(lBw + i * 512), 16, 0, 0);
        }
    };

    stage(0, 0);
    int cur = 0;
    for (int kt = 0; kt < K; kt += BK, cur ^= 1) {
        const bool more = (kt + BK) < K;
        if (more) {
            stage(cur ^ 1, kt + BK);                       // 8 more in flight
            asm volatile("s_waitcnt vmcnt(8)" ::: "memory"); // cur's 8 done
        } else {
            asm volatile("s_waitcnt vmcnt(0)" ::: "memory"); // drain last
        }
        __builtin_amdgcn_s_barrier();
        __builtin_amdgcn_sched_barrier(0);   // keep ds_reads below barrier

        #pragma unroll
        for (int kk = 0; kk < 2; kk++) {
            bf16x8 af[4], bfr[4];
            #pragma unroll
            for (int m = 0; m < 4; m++) {
                int row  = wm * 64 + m * 16 + llo;
                int slot = (kk * 4 + lhi) ^ rsel;
                af[m] = *reinterpret_cast<const bf16x8*>(&As[cur][row * BK + slot * 8]);
            }
            #pragma unroll
            for (int n = 0; n < 4; n++) {
                int col  = wn * 64 + n * 16 + llo;
                int slot = (kk * 4 + lhi) ^ rsel;
                bfr[n] = *reinterpret_cast<const bf16x8*>(&Bs[cur][col * BK + slot * 8]);
            }
            #pragma unroll
            for (int m = 0; m < 4; m++)
                #pragma unroll
                for (int n = 0; n < 4; n++)
                    acc[m][n] = __builtin_amdgcn_mfma_f32_16x16x32_bf16(
                        af[m], bfr[n], acc[m][n], 0, 0, 0);
        }
        __builtin_amdgcn_sched_barrier(0);   // reads complete before barrier
        __builtin_amdgcn_s_barrier();        // WAR: cur free for next stage
    }

    // epilogue: C/D layout col = lane&15, row = (lane>>4)*4 + r  [m89-verified]
    #pragma unroll
    for (int n = 0; n < 4; n++) {
        const long col = tileN + wn * 64 + n * 16 + llo;
        float bv = BIAS ? bias[col] : 0.f;
        #pragma unroll
        for (int m = 0; m < 4; m++) {
            const long row0 = tileM + wm * 64 + m * 16 + lhi * 4;
            #pragma unroll
            for (int r = 0; r < 4; r++) {
                const long row = row0 + r;
                float v = acc[m][n][r] + bv;
                if (SPLIT) {
                    if (col < HIDD)
                        ((u16*)Cout)[row * HIDD + col] = f2b(gelu_exact(v));
                    else
                        ((u16*)Cout2)[row * HIDD + (col - HIDD)] = f2b(v);
                } else {
                    long off = row * N + col;
                    if (RES)   v += res[off];
                    if (OBF16) ((u16*)Cout)[off] = f2b(v);
                    else       ((float*)Cout)[off] = v;
                }
            }
        }
    }
}

// ---------------------------------------------------------------------------
// Causal depthwise conv K=4 over T, per (n,t, 8 channels). vr: [ROWS, HIDD]
// ---------------------------------------------------------------------------
__global__ __launch_bounds__(256)
void conv_k(const u16* __restrict__ vr, const float* __restrict__ cw,
            const float* __restrict__ cb, u16* __restrict__ vout) {
    int idx = blockIdx.x * 256 + threadIdx.x;      // ROWS * 192
    int hb  = (idx % 192) * 8;
    int row = idx / 192;
    int t   = row & (TLEN - 1);
    float acc[8];
    #pragma unroll
    for (int e = 0; e < 8; e++) acc[e] = cb[hb + e];
    #pragma unroll
    for (int j = 0; j < 4; j++) {
        int dt = 3 - j;
        if (t >= dt) {
            u16x8 v = *reinterpret_cast<const u16x8*>(
                vr + (long)(row - dt) * HIDD + hb);
            #pragma unroll
            for (int e = 0; e < 8; e++)
                acc[e] = fmaf(b2f(v[e]), cw[(hb + e) * 4 + j], acc[e]);
        }
    }
    u16x8 o;
    #pragma unroll
    for (int e = 0; e < 8; e++) o[e] = f2b(acc[e]);
    *reinterpret_cast<u16x8*>(vout + (long)row * HIDD + hb) = o;
}

// ---------------------------------------------------------------------------
// Fused scan phase A: recompute alpha/xg from g (forget,inp) + vconv, reduce
// chunk to (A = prod alpha, b = chunk-local scan end value).
// ---------------------------------------------------------------------------
__global__ __launch_bounds__(256)
void scanA_k(const u16* __restrict__ g, const u16* __restrict__ vc,
             const float* __restrict__ fb, float* __restrict__ Ac,
             float* __restrict__ bc) {
    int idx = blockIdx.x * 256 + threadIdx.x;      // 4*NCH*HID = 393216
    int h   = idx % HIDD;
    int nc  = idx / HIDD;                          // n*NCH + c
    const float c = -8.f * log1pf(expf(fb[h]));    // -8*softplus(fbase)
    long row = (long)nc * CH;
    float A = 1.f, b = 0.f;
    for (int t = 0; t < CH; t++, row++) {
        float fg = b2f(g[row * (2*HIDD) + h]);
        float ip = b2f(g[row * (2*HIDD) + HIDD + h]);
        float vv = b2f(vc[row * HIDD + h]);
        float a  = expf(c * sigmoidf_(fg));
        float be = sqrtf(1.f - a * a + 1e-6f);
        float x  = be * sigmoidf_(ip) * vv;
        A *= a;
        b = fmaf(a, b, x);
    }
    Ac[idx] = A;
    bc[idx] = b;
}

__global__ __launch_bounds__(256)
void scanB_k(const float* __restrict__ Ac, const float* __restrict__ bc,
             float* __restrict__ carry) {
    int idx = blockIdx.x * 256 + threadIdx.x;      // 4*HID = 6144
    if (idx >= 4 * HIDD) return;
    int n = idx / HIDD, h = idx % HIDD;
    float H = 0.f;
    #pragma unroll 8
    for (int c = 0; c < NCH; c++) {
        long o = (long)(n * NCH + c) * HIDD + h;
        carry[o] = H;
        H = fmaf(Ac[o], H, bc[o]);
    }
}

// ---------------------------------------------------------------------------
// Fused scan phase C: recompute alpha/xg, finish scan from carry, multiply by
// precomputed gelu(gate) (gg) -> bf16 gh (GEMM3 A-operand).
// ---------------------------------------------------------------------------
__global__ __launch_bounds__(256)
void scanC_k(const u16* __restrict__ g, const u16* __restrict__ vc,
             const float* __restrict__ fb, const float* __restrict__ carry,
             const u16* __restrict__ gg, u16* __restrict__ gh) {
    int idx = blockIdx.x * 256 + threadIdx.x;      // 4*NCH*HID
    int h   = idx % HIDD;
    int nc  = idx / HIDD;
    const float c = -8.f * log1pf(expf(fb[h]));
    float H = carry[idx];
    long row = (long)nc * CH;
    for (int t = 0; t < CH; t++, row++) {
        float fg = b2f(g[row * (2*HIDD) + h]);
        float ip = b2f(g[row * (2*HIDD) + HIDD + h]);
        float vv = b2f(vc[row * HIDD + h]);
        float a  = expf(c * sigmoidf_(fg));
        float be = sqrtf(1.f - a * a + 1e-6f);
        float x  = be * sigmoidf_(ip) * vv;
        H = fmaf(a, H, x);
        float gv = b2f(gg[row * HIDD + h]);
        gh[row * HIDD + h] = f2b(gv * H);
    }
}

// ---------------------------------------------------------------------------
// m2 = gelu(grow[:, :GHID]) * grow[:, GHID:]  -> bf16
// ---------------------------------------------------------------------------
__global__ __launch_bounds__(256)
void glumul_k(const u16* __restrict__ grow, u16* __restrict__ m2) {
    long idx = ((long)blockIdx.x * 256 + threadIdx.x) * 4;  // ROWS*GHID
    int row = (int)(idx >> 11);                    // /2048
    int h   = (int)(idx & (GHIDD - 1));
    u16x4 gt = *reinterpret_cast<const u16x4*>(grow + (long)row * (2*GHIDD) + h);
    u16x4 vv = *reinterpret_cast<const u16x4*>(grow + (long)row * (2*GHIDD) + GHIDD + h);
    u16x4 o;
    #pragma unroll
    for (int e = 0; e < 4; e++)
        o[e] = f2b(gelu_exact(b2f(gt[e])) * b2f(vv[e]));
    *reinterpret_cast<u16x4*>(m2 + idx) = o;
}

// ---------------------------------------------------------------------------
// Launch
// ---------------------------------------------------------------------------
extern "C" void kernel_launch(void* const* d_in, const int* in_sizes, int n_in,
                              void* d_out, int out_size, void* d_ws, size_t ws_size,
                              hipStream_t stream) {
    (void)in_sizes; (void)n_in; (void)out_size; (void)ws_size;
    const float* x        = (const float*)d_in[0];
    const float* gamma1   = (const float*)d_in[1];
    const float* W_in     = (const float*)d_in[2];
    const float* conv_w   = (const float*)d_in[3];
    const float* conv_b   = (const float*)d_in[4];
    const float* W_gates  = (const float*)d_in[5];
    const float* b_gates  = (const float*)d_in[6];
    const float* fbase    = (const float*)d_in[7];
    const float* W_out    = (const float*)d_in[8];
    const float* gamma2   = (const float*)d_in[9];
    const float* W_grow   = (const float*)d_in[10];
    const float* W_shrink = (const float*)d_in[11];

    char* ws = (char*)d_ws;
    // workspace layout (bytes), peak 178,782,208 (~170.5 MB), with aliasing:
    //   vr (gemm1..conv) then gh (scanC..gemm3) share one 25.2 MB slot;
    //   grow (gemm4..glumul) overlays gg+gh+vc (all dead by then);
    //   m2 (glumul..gemm5) overlays g; x2 residual stream lives in d_out.
    u16*   w_in_b    = (u16*)(ws + 0);                 //  6,291,456
    u16*   w_gates_b = (u16*)(ws + 6291456);           //  9,437,184
    u16*   w_out_b   = (u16*)(ws + 15728640);          //  3,145,728
    u16*   w_grow_b  = (u16*)(ws + 18874368);          //  8,388,608
    u16*   w_shr_b   = (u16*)(ws + 27262976);          //  4,194,304
    u16*   xn_b      = (u16*)(ws + 31457280);          // 16.8 MB (xn1 / xn2)
    u16*   gg_b      = (u16*)(ws + 48234496);          // 25.2 MB gelu(gate)
    u16*   vr_b      = (u16*)(ws + 73400320);          // 25.2 MB v raw
    u16*   gh_b      = (u16*)(ws + 73400320);          // alias (vr dead)
    u16*   vc_b      = (u16*)(ws + 98566144);          // 25.2 MB v conv
    u16*   g_b       = (u16*)(ws + 123731968);         // 50.3 MB gates
    u16*   grow_b    = (u16*)(ws + 48234496);          // alias gg..vc (67.1MB)
    u16*   m2_b      = (u16*)(ws + 123731968);         // alias g (33.6 MB)
    float* Ac_f      = (float*)(ws + 174063616);       // 1.57 MB
    float* bc_f      = (float*)(ws + 175636480);       // 1.57 MB
    float* carry_f   = (float*)(ws + 177209344);       // 1.57 MB -> 178,782,208
    float* x2_f      = (float*)d_out;                  // residual stream

    // --- weight conversion ---
    cvt_k<<<3072, 256, 0, stream>>>(W_in,     w_in_b,    (long)3072*1024);
    cvt_k<<<4608, 256, 0, stream>>>(W_gates,  w_gates_b, (long)3072*1536);
    cvt_k<<<1536, 256, 0, stream>>>(W_out,    w_out_b,   (long)1024*1536);
    cvt_k<<<4096, 256, 0, stream>>>(W_grow,   w_grow_b,  (long)4096*1024);
    cvt_k<<<2048, 256, 0, stream>>>(W_shrink, w_shr_b,   (long)1024*2048);

    // --- Hawk branch ---
    rmsnorm_k<<<ROWS, 256, 0, stream>>>(x, gamma1, xn_b);
    gemm_bt<false,false,true,true><<<dim3(3072/128, ROWS/128), 256, 0, stream>>>(
        xn_b, w_in_b, nullptr, nullptr, gg_b, vr_b, ROWS, 3072, 1024);
    conv_k<<<ROWS*192/256, 256, 0, stream>>>(vr_b, conv_w, conv_b, vc_b);
    gemm_bt<true,false,true,false><<<dim3(3072/128, ROWS/128), 256, 0, stream>>>(
        vc_b, w_gates_b, b_gates, nullptr, g_b, nullptr, ROWS, 3072, 1536);
    scanA_k<<<4*NCH*HIDD/256, 256, 0, stream>>>(g_b, vc_b, fbase, Ac_f, bc_f);
    scanB_k<<<24, 256, 0, stream>>>(Ac_f, bc_f, carry_f);
    scanC_k<<<4*NCH*HIDD/256, 256, 0, stream>>>(g_b, vc_b, fbase, carry_f,
                                                gg_b, gh_b);
    gemm_bt<false,true,false,false><<<dim3(1024/128, ROWS/128), 256, 0, stream>>>(
        gh_b, w_out_b, nullptr, x, x2_f, nullptr, ROWS, 1024, 1536);

    // --- GatedMLP branch ---
    rmsnorm_k<<<ROWS, 256, 0, stream>>>(x2_f, gamma2, xn_b);
    gemm_bt<false,false,true,false><<<dim3(4096/128, ROWS/128), 256, 0, stream>>>(
        xn_b, w_grow_b, nullptr, nullptr, grow_b, nullptr, ROWS, 4096, 1024);
    glumul_k<<<(long)ROWS*GHIDD/4/256, 256, 0, stream>>>(grow_b, m2_b);
    gemm_bt<false,true,false,false><<<dim3(1024/128, ROWS/128), 256, 0, stream>>>(
        m2_b, w_shr_b, nullptr, x2_f, (float*)d_out, nullptr, ROWS, 1024, 2048);
}